// Round 1
// baseline (784.583 us; speedup 1.0000x reference)
//
#include <hip/hip_runtime.h>
#include <math.h>

#define NTOT 262144           // 64^3
#define CCH 32
#define PI_F 3.14159265358979323846f

__device__ __forceinline__ float gelu_exact(float v) {
    return 0.5f * v * (1.0f + erff(v * 0.70710678118654752f));
}

// ---------------- emb kernel: embk[b*32+c] = t_emb + c_emb + lift_b ----------------
__global__ void k_emb(const float* __restrict__ time_i, const float* __restrict__ conditions,
                      const float* __restrict__ t_embed_w, const float* __restrict__ t_embed_b,
                      const float* __restrict__ c_embed_w, const float* __restrict__ c_embed_b,
                      const float* __restrict__ lift_b, float* __restrict__ embk) {
    int b = blockIdx.x;
    int c = threadIdx.x;   // 0..31
    float acc = t_embed_b[c] + c_embed_b[c] + lift_b[c];
    // time features: [cos(2^i pi t) i=0..4, sin(...) i=0..4, t]
    float tv = time_i[b];
    {
        float ang = PI_F * tv;
        const float* tw = t_embed_w + c * 11;
        for (int i = 0; i < 5; i++) {
            float s, co; sincosf(ang, &s, &co);
            acc += co * tw[i] + s * tw[5 + i];
            ang *= 2.0f;
        }
        acc += tv * tw[10];
    }
    // condition features: per l: [cos x5, sin x5], then raw (offset 320)
    {
        const float* cw = c_embed_w + c * 352;
        for (int l = 0; l < 32; l++) {
            float v = conditions[b * 32 + l];
            float ang = PI_F * v;
            for (int i = 0; i < 5; i++) {
                float s, co; sincosf(ang, &s, &co);
                acc += co * cw[l * 10 + i] + s * cw[l * 10 + 5 + i];
                ang *= 2.0f;
            }
            acc += v * cw[320 + l];
        }
    }
    embk[b * 32 + c] = acc;
}

// ---------------- lift: x0[b][o][n] = lift_w @ feat(n) + embk ----------------
__global__ void k_lift(const float* __restrict__ state_in, const float* __restrict__ node_pos,
                       const float* __restrict__ lift_w, const float* __restrict__ embk,
                       float* __restrict__ x0) {
    __shared__ float lw[32 * 37];
    __shared__ float eb[64];
    int t = threadIdx.x;
    for (int idx = t; idx < 32 * 37; idx += 256) lw[idx] = lift_w[idx];
    if (t < 64) eb[t] = embk[t];
    __syncthreads();

    int g = blockIdx.x * 256 + t;
    int b = g >> 18;
    int n = g & (NTOT - 1);

    float f[37];
    const float* sp = state_in + ((size_t)(b) * NTOT + n) * 4;
    f[0] = sp[0]; f[1] = sp[1]; f[2] = sp[2]; f[3] = sp[3];
    const float* pp = node_pos + ((size_t)(b) * NTOT + n) * 3;
    for (int l = 0; l < 3; l++) {
        float p = pp[l];
        float ang = PI_F * p;
        for (int i = 0; i < 5; i++) {
            float s, co; sincosf(ang, &s, &co);
            f[4 + l * 10 + i] = co;
            f[4 + l * 10 + 5 + i] = s;
            ang *= 2.0f;
        }
        f[34 + l] = p;
    }
    for (int o = 0; o < 32; o++) {
        float acc = eb[b * 32 + o];
        const float* w = lw + o * 37;
        for (int k = 0; k < 37; k++) acc += w[k] * f[k];
        x0[(((size_t)(b * 32 + o)) << 18) + n] = acc;
    }
}

// ---------------- forward Z + Y DFT: per (b,c,nx) slab ----------------
// out: a2[b][c][kz][ky][nx]
__global__ void k_fzy(const float* __restrict__ xin, float* __restrict__ a2r, float* __restrict__ a2i) {
    __shared__ float xs[64 * 65];
    __shared__ float a1r[8 * 65], a1i[8 * 65];
    __shared__ float cosT[64], sinT[64];
    int t = threadIdx.x;
    int bc = blockIdx.x >> 6;
    int nx = blockIdx.x & 63;
    if (t < 64) { float s, c; sincosf((float)t * (PI_F / 32.0f), &s, &c); cosT[t] = c; sinT[t] = s; }
    const float* src = xin + (((size_t)bc) << 18) + (nx << 12);
    for (int idx = t; idx < 4096; idx += 256) xs[(idx >> 6) * 65 + (idx & 63)] = src[idx];
    __syncthreads();

    int ny = t & 63;
    int kz0 = t >> 6;   // 0..3
    for (int p = 0; p < 2; p++) {
        int kz = kz0 + p * 4;
        float re = 0.0f, im = 0.0f;
        for (int nz = 0; nz < 64; nz++) {
            float v = xs[ny * 65 + nz];
            int m = (kz * nz) & 63;
            re += v * cosT[m];
            im -= v * sinT[m];
        }
        a1r[kz * 65 + ny] = re;
        a1i[kz * 65 + ny] = im;
    }
    __syncthreads();
    if (t < 64) {
        int kz = t >> 3, ky = t & 7;
        float rr = 0.0f, ri = 0.0f;
        for (int n2 = 0; n2 < 64; n2++) {
            float ar = a1r[kz * 65 + n2], ai = a1i[kz * 65 + n2];
            int m = (ky * n2) & 63;
            float c = cosT[m], s = sinT[m];
            rr += ar * c + ai * s;     // (ar + i ai)(c - i s)
            ri += ai * c - ar * s;
        }
        int o = ((bc * 8 + kz) * 8 + ky) * 64 + nx;
        a2r[o] = rr; a2i[o] = ri;
    }
}

// ---------------- forward X DFT: per (b,c); out Xft[b][c][kz][ky][kx] ----------------
__global__ void k_fx(const float* __restrict__ a2r, const float* __restrict__ a2i,
                     float* __restrict__ xftr, float* __restrict__ xfti) {
    __shared__ float lr[64 * 65], li[64 * 65];
    __shared__ float cosT[64], sinT[64];
    int t = threadIdx.x;
    int bc = blockIdx.x;
    if (t < 64) { float s, c; sincosf((float)t * (PI_F / 32.0f), &s, &c); cosT[t] = c; sinT[t] = s; }
    for (int idx = t; idx < 4096; idx += 256) {
        int kzky = idx >> 6, nx = idx & 63;
        lr[kzky * 65 + nx] = a2r[bc * 4096 + idx];
        li[kzky * 65 + nx] = a2i[bc * 4096 + idx];
    }
    __syncthreads();
    for (int p = 0; p < 2; p++) {
        int idx = t + p * 256;     // 0..511 : kz*64 + ky*8 + kx
        int kzky = idx >> 3;
        int kx = idx & 7;
        float rr = 0.0f, ri = 0.0f;
        for (int nx = 0; nx < 64; nx++) {
            float ar = lr[kzky * 65 + nx], ai = li[kzky * 65 + nx];
            int m = (kx * nx) & 63;
            float c = cosT[m], s = sinT[m];
            rr += ar * c + ai * s;
            ri += ai * c - ar * s;
        }
        xftr[bc * 512 + idx] = rr;
        xfti[bc * 512 + idx] = ri;
    }
}

// ---------------- mode mix: per (b,kx,ky); Yft[b][o][kz][ky][kx] = sum_i Xft*W ----------------
__global__ void k_mix(const float* __restrict__ xftr, const float* __restrict__ xfti,
                      const float* __restrict__ wr, const float* __restrict__ wi,
                      float* __restrict__ yftr, float* __restrict__ yfti) {
    __shared__ float lxr[32 * 8], lxi[32 * 8];
    int t = threadIdx.x;
    int b = blockIdx.x >> 6;
    int kx = (blockIdx.x >> 3) & 7;
    int ky = blockIdx.x & 7;
    {
        int i = t >> 3, kz = t & 7;
        int a = ((b * 32 + i) << 9) + kz * 64 + ky * 8 + kx;
        lxr[t] = xftr[a];
        lxi[t] = xfti[a];
    }
    __syncthreads();
    int o = t >> 3, kz = t & 7;
    float yr = 0.0f, yi = 0.0f;
    for (int i = 0; i < 32; i++) {
        float xr = lxr[i * 8 + kz], xi = lxi[i * 8 + kz];
        int wofs = ((i * 32 + o) << 9) + kx * 64 + ky * 8 + kz;   // w[i][o][kx][ky][kz]
        float wrv = wr[wofs], wiv = wi[wofs];
        yr += xr * wrv - xi * wiv;
        yi += xr * wiv + xi * wrv;
    }
    int a = ((b * 32 + o) << 9) + kz * 64 + ky * 8 + kx;
    yftr[a] = yr;
    yfti[a] = yi;
}

// ---------------- inverse X + Y: per (b,o,kz); out B2[b][o][kz][nx][ny] ----------------
__global__ void k_ixy(const float* __restrict__ yftr, const float* __restrict__ yfti,
                      float* __restrict__ b2r, float* __restrict__ b2i) {
    __shared__ float lyr[64], lyi[64];
    __shared__ float b1r[512], b1i[512];
    __shared__ float cosT[64], sinT[64];
    int t = threadIdx.x;
    int bo = blockIdx.x >> 3;
    int kz = blockIdx.x & 7;
    if (t < 64) { float s, c; sincosf((float)t * (PI_F / 32.0f), &s, &c); cosT[t] = c; sinT[t] = s; }
    if (t < 64) {
        lyr[t] = yftr[(bo << 9) + (kz << 6) + t];   // t = ky*8+kx
        lyi[t] = yfti[(bo << 9) + (kz << 6) + t];
    }
    __syncthreads();
    for (int p = 0; p < 2; p++) {
        int idx = t + p * 256;         // ky*64 + nx
        int ky = idx >> 6, nx = idx & 63;
        float rr = 0.0f, ri = 0.0f;
        for (int kx = 0; kx < 8; kx++) {
            float yr = lyr[ky * 8 + kx], yi = lyi[ky * 8 + kx];
            int m = (kx * nx) & 63;
            float c = cosT[m], s = sinT[m];
            rr += yr * c - yi * s;     // e^{+i}
            ri += yr * s + yi * c;
        }
        b1r[idx] = rr;
        b1i[idx] = ri;
    }
    __syncthreads();
    int ny = t & 63;
    int nx0 = t >> 6;      // 0..3
    for (int j = 0; j < 16; j++) {
        int nx = nx0 + 4 * j;
        float rr = 0.0f, ri = 0.0f;
        for (int ky = 0; ky < 8; ky++) {
            float br = b1r[ky * 64 + nx], bi = b1i[ky * 64 + nx];
            int m = (ky * ny) & 63;
            float c = cosT[m], s = sinT[m];
            rr += br * c - bi * s;
            ri += br * s + bi * c;
        }
        size_t a = (((size_t)bo * 8 + kz) << 12) + nx * 64 + ny;
        b2r[a] = rr;
        b2i[a] = ri;
    }
}

// ---------------- final: inverse Z + bypass conv + gelu, per (b,nx,ny) column ----------------
__global__ void k_fin(const float* __restrict__ xin, const float* __restrict__ b2r,
                      const float* __restrict__ b2i, const float* __restrict__ bw,
                      const float* __restrict__ bb, float* __restrict__ xout) {
    __shared__ float xs[32 * 64];
    __shared__ float wb[32 * 32];
    __shared__ float lb2r[256], lb2i[256];
    __shared__ float cosT[64], sinT[64];
    __shared__ float bias[32];
    int t = threadIdx.x;
    int b = blockIdx.x >> 12;
    int nxy = blockIdx.x & 4095;
    if (t < 64) { float s, c; sincosf((float)t * (PI_F / 32.0f), &s, &c); cosT[t] = c; sinT[t] = s; }
    for (int idx = t; idx < 1024; idx += 256) wb[idx] = bw[idx];
    if (t < 32) bias[t] = bb[t];
    for (int idx = t; idx < 2048; idx += 256) {
        int i = idx >> 6, nz = idx & 63;
        xs[idx] = xin[(((size_t)(b * 32 + i)) << 18) + (nxy << 6) + nz];
    }
    {
        int o = t >> 3, kz = t & 7;
        size_t a = (((size_t)((b * 32 + o) * 8 + kz)) << 12) + nxy;
        lb2r[t] = b2r[a];
        lb2i[t] = b2i[a];
    }
    __syncthreads();
    int nz = t & 63;
    int o0 = t >> 6;      // 0..3
    const float scale = 1.0f / 262144.0f;
    for (int k = 0; k < 8; k++) {
        int o = o0 + 4 * k;
        float bp = bias[o];
        const float* w = wb + o * 32;
        for (int i = 0; i < 32; i++) bp += w[i] * xs[i * 64 + nz];
        float sp = lb2r[o * 8 + 0];
        for (int kz = 1; kz < 8; kz++) {
            int m = (kz * nz) & 63;
            sp += 2.0f * (lb2r[o * 8 + kz] * cosT[m] - lb2i[o * 8 + kz] * sinT[m]);
        }
        float v = sp * scale + bp;
        xout[(((size_t)(b * 32 + o)) << 18) + (nxy << 6) + nz] = gelu_exact(v);
    }
}

// ---------------- projection: gelu(W1 x + b1) -> W2 -> residual ----------------
__global__ void k_proj(const float* __restrict__ x4, const float* __restrict__ w1,
                       const float* __restrict__ b1, const float* __restrict__ w2,
                       const float* __restrict__ b2, const float* __restrict__ state_in,
                       float* __restrict__ out) {
    __shared__ float lw1[32 * 32];
    __shared__ float lb1[32];
    __shared__ float lw2[4 * 32];
    __shared__ float lb2[4];
    int t = threadIdx.x;
    for (int idx = t; idx < 1024; idx += 256) lw1[idx] = w1[idx];
    if (t < 32) lb1[t] = b1[t];
    if (t < 128) lw2[t] = w2[t];
    if (t < 4) lb2[t] = b2[t];
    __syncthreads();
    int g = blockIdx.x * 256 + t;
    int b = g >> 18;
    int n = g & (NTOT - 1);
    float xv[32];
    for (int i = 0; i < 32; i++) xv[i] = x4[(((size_t)(b * 32 + i)) << 18) + n];
    float h[32];
    for (int o = 0; o < 32; o++) {
        float acc = lb1[o];
        const float* w = lw1 + o * 32;
        for (int i = 0; i < 32; i++) acc += w[i] * xv[i];
        h[o] = gelu_exact(acc);
    }
    size_t base = ((size_t)b * NTOT + n) * 4;
    for (int j = 0; j < 4; j++) {
        float acc = lb2[j];
        const float* w = lw2 + j * 32;
        for (int o = 0; o < 32; o++) acc += w[o] * h[o];
        out[base + j] = state_in[base + j] + 0.05f * acc;
    }
}

extern "C" void kernel_launch(void* const* d_in, const int* in_sizes, int n_in,
                              void* d_out, int out_size, void* d_ws, size_t ws_size,
                              hipStream_t stream) {
    const float* state_in   = (const float*)d_in[0];
    const float* node_pos   = (const float*)d_in[1];
    const float* time_i     = (const float*)d_in[3];
    const float* conditions = (const float*)d_in[4];
    const float* t_embed_w  = (const float*)d_in[5];
    const float* t_embed_b  = (const float*)d_in[6];
    const float* c_embed_w  = (const float*)d_in[7];
    const float* c_embed_b  = (const float*)d_in[8];
    const float* lift_w     = (const float*)d_in[9];
    const float* lift_b     = (const float*)d_in[10];
    const float* spec_wr    = (const float*)d_in[11];
    const float* spec_wi    = (const float*)d_in[12];
    const float* byp_w      = (const float*)d_in[13];
    const float* byp_b      = (const float*)d_in[14];
    const float* proj1_w    = (const float*)d_in[15];
    const float* proj1_b    = (const float*)d_in[16];
    const float* proj2_w    = (const float*)d_in[17];
    const float* proj2_b    = (const float*)d_in[18];
    float* out = (float*)d_out;
    float* ws  = (float*)d_ws;

    float* xA   = ws;
    float* xB   = ws + 16777216;
    float* a2r  = ws + 33554432;
    float* a2i  = a2r + 262144;
    float* xftr = a2i + 262144;
    float* xfti = xftr + 32768;
    float* yftr = xfti + 32768;
    float* yfti = yftr + 32768;
    float* b2r  = yfti + 32768;
    float* b2i  = b2r + 2097152;
    float* embk = b2i + 2097152;

    k_emb<<<2, 32, 0, stream>>>(time_i, conditions, t_embed_w, t_embed_b,
                                c_embed_w, c_embed_b, lift_b, embk);
    k_lift<<<2048, 256, 0, stream>>>(state_in, node_pos, lift_w, embk, xA);

    for (int l = 0; l < 4; l++) {
        float* xin  = (l & 1) ? xB : xA;
        float* xout = (l & 1) ? xA : xB;
        k_fzy<<<4096, 256, 0, stream>>>(xin, a2r, a2i);
        k_fx<<<64, 256, 0, stream>>>(a2r, a2i, xftr, xfti);
        k_mix<<<128, 256, 0, stream>>>(xftr, xfti, spec_wr + (size_t)l * 524288,
                                       spec_wi + (size_t)l * 524288, yftr, yfti);
        k_ixy<<<512, 256, 0, stream>>>(yftr, yfti, b2r, b2i);
        k_fin<<<8192, 256, 0, stream>>>(xin, b2r, b2i, byp_w + l * 1024, byp_b + l * 32, xout);
    }

    k_proj<<<2048, 256, 0, stream>>>(xA, proj1_w, proj1_b, proj2_w, proj2_b, state_in, out);
}